// Round 4
// baseline (13728.552 us; speedup 1.0000x reference)
//
#include <hip/hip_runtime.h>
#include <hip/hip_bf16.h>
#include <cmath>

#define LSEQ 256
#define BB   128
#define DD   2048
#define HH   2048
#define BH   (BB*HH)
#define NBLK 256   // persistent scan grid: must be <= #CUs (256) for residency

typedef __attribute__((ext_vector_type(8))) short short8;   // 8 bf16
typedef __attribute__((ext_vector_type(4))) short short4v;  // 4 bf16
typedef __attribute__((ext_vector_type(4))) float f32x4;

// fp32 -> bf16 hi/lo truncation split; hi*hi + hi*lo + lo*hi ~ 2^-16 rel.
__device__ __forceinline__ void split2(float x, short& hi, short& lo) {
    unsigned u = __float_as_uint(x);
    hi = (short)(u >> 16);
    float r = x - __uint_as_float(u & 0xffff0000u);
    lo = (short)(__float_as_uint(r) >> 16);
}

#define MFMA(a, b, c) __builtin_amdgcn_mfma_f32_16x16x32_bf16((a), (b), (c), 0, 0, 0)

// ---------------------------------------------------------------------------
// Prep: W [2048][2048] fp32 (k-major) -> outH/outL [n][k] bf16 planes.
// ---------------------------------------------------------------------------
__global__ __launch_bounds__(256) void transpose_split(const float* __restrict__ W,
                                                       short* __restrict__ outH,
                                                       short* __restrict__ outL) {
    __shared__ float S[64][65];
    const int tid = threadIdx.x;
    const int r0 = blockIdx.x * 64;   // k tile
    const int c0 = blockIdx.y * 64;   // n tile
    const int lr = tid >> 2;          // 0..63
    const int lc = (tid & 3) * 16;
#pragma unroll
    for (int j = 0; j < 4; ++j) {
        f32x4 v = *(const f32x4*)&W[(size_t)(r0 + lr) * DD + c0 + lc + 4*j];
#pragma unroll
        for (int q = 0; q < 4; ++q) S[lr][lc + 4*j + q] = v[q];
    }
    __syncthreads();
    short8 h8[2], l8[2];
#pragma unroll
    for (int j = 0; j < 16; ++j) {
        short h, l;
        split2(S[lc + j][lr], h, l);
        h8[j >> 3][j & 7] = h; l8[j >> 3][j & 7] = l;
    }
    const size_t o = (size_t)(c0 + lr) * DD + r0 + lc;
    *(short8*)&outH[o]     = h8[0];
    *(short8*)&outH[o + 8] = h8[1];
    *(short8*)&outL[o]     = l8[0];
    *(short8*)&outL[o + 8] = l8[1];
}

// ---------------------------------------------------------------------------
// xp = X @ W_ih + b  (split-3 bf16 GEMM). 128x128 tile, 4 waves (2x2).
// Unchanged from round 3. rt==0 blocks fuse tanh + h0-plane emit.
// ---------------------------------------------------------------------------
__global__ __launch_bounds__(256) void xp_gemm(const float* __restrict__ X,
                                               const short* __restrict__ WTh,
                                               const short* __restrict__ WTl,
                                               const float* __restrict__ bias,
                                               float* __restrict__ C,
                                               short* __restrict__ h0H,
                                               short* __restrict__ h0L) {
    __shared__ short Ah_s[128 * 40];
    __shared__ short Al_s[128 * 40];

    const int tid = threadIdx.x, lane = tid & 63, wave = tid >> 6;
    const int l15 = lane & 15, lg = lane >> 4;

    const int gid = blockIdx.x;
    const int rt = ((gid >> 8) << 4) | (gid & 15);
    const int ct = (gid >> 4) & 15;
    const int row0 = rt * 128, col0 = ct * 128;
    const int wm = (wave >> 1) * 64, wn = (wave & 1) * 64;

    const int sr = tid >> 3, sc = (tid & 7) * 4;
    const float* gA = X + (size_t)(row0 + sr) * DD + sc;

    size_t brow[4];
#pragma unroll
    for (int n = 0; n < 4; ++n)
        brow[n] = (size_t)(col0 + wn + n * 16 + l15) * DD + lg * 8;

    f32x4 acc[4][4] = {};

    for (int k0 = 0; k0 < DD; k0 += 32) {
        f32x4 av[4];
        short4v h4[4], l4[4];
#pragma unroll
        for (int i = 0; i < 4; ++i)
            av[i] = *(const f32x4*)(gA + (size_t)(32 * i) * DD + k0);
#pragma unroll
        for (int i = 0; i < 4; ++i)
#pragma unroll
            for (int q = 0; q < 4; ++q) {
                short h, l; split2(av[i][q], h, l);
                h4[i][q] = h; l4[i][q] = l;
            }
        short8 bh[4], bl[4];
#pragma unroll
        for (int n = 0; n < 4; ++n) {
            bh[n] = *(const short8*)&WTh[brow[n] + k0];
            bl[n] = *(const short8*)&WTl[brow[n] + k0];
        }
        __syncthreads();
#pragma unroll
        for (int i = 0; i < 4; ++i) {
            *(short4v*)&Ah_s[(sr + 32 * i) * 40 + sc] = h4[i];
            *(short4v*)&Al_s[(sr + 32 * i) * 40 + sc] = l4[i];
        }
        __syncthreads();
        short8 ah[4], al[4];
#pragma unroll
        for (int m = 0; m < 4; ++m) {
            const int ro = (wm + m * 16 + l15) * 40 + lg * 8;
            ah[m] = *(const short8*)&Ah_s[ro];
            al[m] = *(const short8*)&Al_s[ro];
        }
#pragma unroll
        for (int m = 0; m < 4; ++m)
#pragma unroll
            for (int n = 0; n < 4; ++n) {
                acc[m][n] = MFMA(ah[m], bh[n], acc[m][n]);
                acc[m][n] = MFMA(ah[m], bl[n], acc[m][n]);
                acc[m][n] = MFMA(al[m], bh[n], acc[m][n]);
            }
    }

    float bv[4];
#pragma unroll
    for (int n = 0; n < 4; ++n) bv[n] = bias[col0 + wn + n * 16 + l15];

    if (rt == 0) {
#pragma unroll
        for (int m = 0; m < 4; ++m)
#pragma unroll
            for (int n = 0; n < 4; ++n)
#pragma unroll
                for (int i = 0; i < 4; ++i) {
                    const int row = wm + m * 16 + lg * 4 + i;
                    const int col = col0 + wn + n * 16 + l15;
                    const float t = tanhf(acc[m][n][i] + bv[n]);
                    const size_t o = (size_t)row * HH + col;
                    C[o] = t;
                    short h, l; split2(t, h, l);
                    h0H[o] = h; h0L[o] = l;
                }
    } else {
#pragma unroll
        for (int m = 0; m < 4; ++m)
#pragma unroll
            for (int n = 0; n < 4; ++n)
#pragma unroll
                for (int i = 0; i < 4; ++i) {
                    const int row = row0 + wm + m * 16 + lg * 4 + i;
                    const int col = col0 + wn + n * 16 + l15;
                    C[(size_t)row * HH + col] = acc[m][n][i] + bv[n];
                }
    }
}

// ---------------------------------------------------------------------------
// Persistent scan kernel: all 255 steps in ONE dispatch with a manual grid
// barrier. 256 blocks x 512 threads; block (mr,nc) owns the 32x32 output tile
// rows mr*32.., cols nc*32..; bid = mr*64+nc puts a strip's 4 blocks on one
// XCD (64%8==0). W_hh-hi slice (32 cols x 2048 K bf16 = 128KB) is loaded into
// LDS ONCE (XOR-swizzled), immune to per-step cache invalidation; W-lo + h
// planes stream from L2/L3. 8-wave K-split (256 each), two-phase LDS reduce.
// Residency proof: LDS 144KB -> 1 block/CU; 256 blocks <= 256 CUs.
// ---------------------------------------------------------------------------
__global__ __launch_bounds__(512) void rnn_scan(const short* __restrict__ WTh,
                                                const short* __restrict__ WTl,
                                                short* __restrict__ hA_hi, short* __restrict__ hA_lo,
                                                short* __restrict__ hB_hi, short* __restrict__ hB_lo,
                                                float* __restrict__ out,
                                                float* __restrict__ final_state,
                                                unsigned* barrier_cnt, unsigned* barrier_gen) {
    __shared__ short Whi[32 * 2048];    // 128 KB: W-hi slice, swizzled
    __shared__ float red[4][1024];      // 16 KB: cross-wave reduce

    const int tid = threadIdx.x, lane = tid & 63, wave = tid >> 6;
    const int l15 = lane & 15, lg = lane >> 4;
    const int mr = blockIdx.x >> 6, nc = blockIdx.x & 63;
    const int m0 = mr * 32, n0 = nc * 32;

    // ---- one-time LDS fill of the W-hi strip (swizzle: byte ^= (col&7)<<4) ----
    for (int it = 0; it < 16; ++it) {
        const int ci  = it * 512 + tid;   // 8192 16B-chunks
        const int col = ci >> 8;          // 0..31
        const int kc  = ci & 255;
        const short8 v = *(const short8*)&WTh[(size_t)(n0 + col) * HH + kc * 8];
        const int byte = ((col << 12) + (kc << 4)) ^ ((col & 7) << 4);
        *(short8*)((char*)Whi + byte) = v;
    }
    __syncthreads();

    // per-thread constant addresses
    const size_t a0 = (size_t)(m0 + l15) * HH;
    const size_t a1 = a0 + (size_t)16 * HH;
    const size_t b0 = (size_t)(n0 + l15) * HH;
    const size_t b1 = b0 + (size_t)16 * HH;
    const int kbase = wave * 256 + lg * 8;
    const int c0b = l15, c1b = 16 + l15;
    const int colbase0 = c0b << 12, swz0 = (c0b & 7) << 4;
    const int colbase1 = c1b << 12, swz1 = (c1b & 7) << 4;

    const int e = tid * 2, er = e >> 5, ec = e & 31;       // epilogue coords
    const size_t po = (size_t)(m0 + er) * HH + n0 + ec;

    for (int t = 1; t < LSEQ; ++t) {
        const short* hHp = (t & 1) ? hA_hi : hB_hi;   // prev parity (t-1)&1
        const short* hLp = (t & 1) ? hA_lo : hB_lo;
        short* oH = (t & 1) ? hB_hi : hA_hi;
        short* oL = (t & 1) ? hB_lo : hA_lo;
        float* io = out + (size_t)t * BH;

        f32x4 acc00 = {}, acc01 = {}, acc10 = {}, acc11 = {};
#pragma unroll
        for (int kt = 0; kt < 8; ++kt) {
            const int k = kbase + kt * 32;
            const short8 ah0 = *(const short8*)&hHp[a0 + k];
            const short8 ah1 = *(const short8*)&hHp[a1 + k];
            const short8 al0 = *(const short8*)&hLp[a0 + k];
            const short8 al1 = *(const short8*)&hLp[a1 + k];
            const short8 bl0 = *(const short8*)&WTl[b0 + k];
            const short8 bl1 = *(const short8*)&WTl[b1 + k];
            const short8 bh0 = *(const short8*)((const char*)Whi + (colbase0 | ((2 * k) ^ swz0)));
            const short8 bh1 = *(const short8*)((const char*)Whi + (colbase1 | ((2 * k) ^ swz1)));

            acc00 = MFMA(ah0, bh0, acc00); acc00 = MFMA(ah0, bl0, acc00); acc00 = MFMA(al0, bh0, acc00);
            acc01 = MFMA(ah0, bh1, acc01); acc01 = MFMA(ah0, bl1, acc01); acc01 = MFMA(al0, bh1, acc01);
            acc10 = MFMA(ah1, bh0, acc10); acc10 = MFMA(ah1, bl0, acc10); acc10 = MFMA(al1, bh0, acc10);
            acc11 = MFMA(ah1, bh1, acc11); acc11 = MFMA(ah1, bl1, acc11); acc11 = MFMA(al1, bh1, acc11);
        }

        // two-phase cross-wave reduce (8 partials -> red[0..3] summed pairs)
        f32x4 am[2][2] = {{acc00, acc01}, {acc10, acc11}};
        if (wave < 4) {
#pragma unroll
            for (int m = 0; m < 2; ++m)
#pragma unroll
                for (int n = 0; n < 2; ++n)
#pragma unroll
                    for (int i = 0; i < 4; ++i)
                        red[wave][(m * 16 + lg * 4 + i) * 32 + n * 16 + l15] = am[m][n][i];
        }
        __syncthreads();
        if (wave >= 4) {
#pragma unroll
            for (int m = 0; m < 2; ++m)
#pragma unroll
                for (int n = 0; n < 2; ++n)
#pragma unroll
                    for (int i = 0; i < 4; ++i)
                        red[wave - 4][(m * 16 + lg * 4 + i) * 32 + n * 16 + l15] += am[m][n][i];
        }
        __syncthreads();

        // epilogue: 2 elems/thread — sum 4 partials + xp + tanh, emit planes
        {
            float* iop = io + po;
            const float2 xv = *(const float2*)iop;   // issue before ds_reads
            const int base = er * 32 + ec;
            const float2 r0 = *(const float2*)&red[0][base];
            const float2 r1 = *(const float2*)&red[1][base];
            const float2 r2 = *(const float2*)&red[2][base];
            const float2 r3 = *(const float2*)&red[3][base];
            const float t0 = tanhf(xv.x + r0.x + r1.x + r2.x + r3.x);
            const float t1 = tanhf(xv.y + r0.y + r1.y + r2.y + r3.y);
            *(float2*)iop = make_float2(t0, t1);
            short h0s, l0s, h1s, l1s;
            split2(t0, h0s, l0s); split2(t1, h1s, l1s);
            *(unsigned*)&oH[po] = (unsigned)(unsigned short)h0s | ((unsigned)(unsigned short)h1s << 16);
            *(unsigned*)&oL[po] = (unsigned)(unsigned short)l0s | ((unsigned)(unsigned short)l1s << 16);
            if (t == LSEQ - 1)
                *(float2*)(final_state + po) = make_float2(t0, t1);
        }

        // grid barrier (skip after the last step; kernel-end releases writes)
        if (t != LSEQ - 1) {
            __syncthreads();
            if (tid == 0) {
                __threadfence();   // release our h-plane writes
                unsigned g = __hip_atomic_load(barrier_gen, __ATOMIC_ACQUIRE, __HIP_MEMORY_SCOPE_AGENT);
                unsigned a = __hip_atomic_fetch_add(barrier_cnt, 1u, __ATOMIC_ACQ_REL, __HIP_MEMORY_SCOPE_AGENT);
                if (a == NBLK - 1) {
                    __hip_atomic_store(barrier_cnt, 0u, __ATOMIC_RELAXED, __HIP_MEMORY_SCOPE_AGENT);
                    __hip_atomic_fetch_add(barrier_gen, 1u, __ATOMIC_RELEASE, __HIP_MEMORY_SCOPE_AGENT);
                } else {
                    while (__hip_atomic_load(barrier_gen, __ATOMIC_ACQUIRE, __HIP_MEMORY_SCOPE_AGENT) == g)
                        __builtin_amdgcn_s_sleep(2);
                }
                __threadfence();   // acquire others' h-plane writes
            }
            __syncthreads();
        }
    }
}

// ---------------------------------------------------------------------------
extern "C" void kernel_launch(void* const* d_in, const int* in_sizes, int n_in,
                              void* d_out, int out_size, void* d_ws, size_t ws_size,
                              hipStream_t stream) {
    (void)in_sizes; (void)n_in; (void)out_size; (void)ws_size;

    const float* X   = (const float*)d_in[0];
    const float* Wih = (const float*)d_in[1];
    const float* Whh = (const float*)d_in[2];
    const float* b   = (const float*)d_in[3];
    float* out = (float*)d_out;

    char* ws = (char*)d_ws;
    short* WihTh = (short*)(ws);
    short* WihTl = (short*)(ws + (size_t) 8*1024*1024);
    short* WhhTh = (short*)(ws + (size_t)16*1024*1024);
    short* WhhTl = (short*)(ws + (size_t)24*1024*1024);
    short* hA_hi = (short*)(ws + (size_t)32*1024*1024);
    short* hA_lo = (short*)(ws + (size_t)32*1024*1024 + 512*1024);
    short* hB_hi = (short*)(ws + (size_t)33*1024*1024);
    short* hB_lo = (short*)(ws + (size_t)33*1024*1024 + 512*1024);
    unsigned* bar = (unsigned*)(ws + (size_t)34*1024*1024);   // [cnt, gen]

    // zero barrier state each call (ws is poisoned 0xAA once, never restored)
    hipMemsetAsync(bar, 0, 2 * sizeof(unsigned), stream);

    dim3 tg(32, 32);
    transpose_split<<<tg, 256, 0, stream>>>(Wih, WihTh, WihTl);
    transpose_split<<<tg, 256, 0, stream>>>(Whh, WhhTh, WhhTl);

    // xp GEMM (t=0 blocks also produce h0 = tanh(xp[0]) + planes into hA)
    xp_gemm<<<4096, 256, 0, stream>>>(X, WihTh, WihTl, b, out, hA_hi, hA_lo);

    // persistent scan: t = 1..255 in one dispatch, writes final state too
    rnn_scan<<<NBLK, 512, 0, stream>>>(WhhTh, WhhTl, hA_hi, hA_lo, hB_hi, hB_lo,
                                       out, out + (size_t)LSEQ * BH, bar, bar + 1);
}

// Round 5
// 5683.764 us; speedup vs baseline: 2.4154x; 2.4154x over previous
//
#include <hip/hip_runtime.h>
#include <hip/hip_bf16.h>
#include <cmath>

#define LSEQ 256
#define BB   128
#define DD   2048
#define HH   2048
#define BH   (BB*HH)
#define NBLK 256   // persistent scan grid: <= #CUs (256) for guaranteed residency

typedef __attribute__((ext_vector_type(8))) short short8;   // 8 bf16
typedef __attribute__((ext_vector_type(4))) short short4v;  // 4 bf16
typedef __attribute__((ext_vector_type(4))) float f32x4;

// fp32 -> bf16 hi/lo truncation split; hi*hi + hi*lo + lo*hi ~ 2^-16 rel.
__device__ __forceinline__ void split2(float x, short& hi, short& lo) {
    unsigned u = __float_as_uint(x);
    hi = (short)(u >> 16);
    float r = x - __uint_as_float(u & 0xffff0000u);
    lo = (short)(__float_as_uint(r) >> 16);
}

#define MFMA(a, b, c) __builtin_amdgcn_mfma_f32_16x16x32_bf16((a), (b), (c), 0, 0, 0)

// 16B coherent load from the h exchange planes: two relaxed AGENT-scope 8B
// atomic loads -> global_load_dwordx2 with sc1 (bypass L1/L2, read from L3).
// No cache-maintenance instructions are ever generated on this path.
__device__ __forceinline__ short8 load_h16(const short* p) {
    unsigned long long u0 = __hip_atomic_load((const unsigned long long*)p,
                                              __ATOMIC_RELAXED, __HIP_MEMORY_SCOPE_AGENT);
    unsigned long long u1 = __hip_atomic_load((const unsigned long long*)(p + 4),
                                              __ATOMIC_RELAXED, __HIP_MEMORY_SCOPE_AGENT);
    union { unsigned long long u[2]; short8 s; } r;
    r.u[0] = u0; r.u[1] = u1;
    return r.s;
}

// ---------------------------------------------------------------------------
// Prep: W [2048][2048] fp32 (k-major) -> outH/outL [n][k] bf16 planes.
// ---------------------------------------------------------------------------
__global__ __launch_bounds__(256) void transpose_split(const float* __restrict__ W,
                                                       short* __restrict__ outH,
                                                       short* __restrict__ outL) {
    __shared__ float S[64][65];
    const int tid = threadIdx.x;
    const int r0 = blockIdx.x * 64;   // k tile
    const int c0 = blockIdx.y * 64;   // n tile
    const int lr = tid >> 2;          // 0..63
    const int lc = (tid & 3) * 16;
#pragma unroll
    for (int j = 0; j < 4; ++j) {
        f32x4 v = *(const f32x4*)&W[(size_t)(r0 + lr) * DD + c0 + lc + 4*j];
#pragma unroll
        for (int q = 0; q < 4; ++q) S[lr][lc + 4*j + q] = v[q];
    }
    __syncthreads();
    short8 h8[2], l8[2];
#pragma unroll
    for (int j = 0; j < 16; ++j) {
        short h, l;
        split2(S[lc + j][lr], h, l);
        h8[j >> 3][j & 7] = h; l8[j >> 3][j & 7] = l;
    }
    const size_t o = (size_t)(c0 + lr) * DD + r0 + lc;
    *(short8*)&outH[o]     = h8[0];
    *(short8*)&outH[o + 8] = h8[1];
    *(short8*)&outL[o]     = l8[0];
    *(short8*)&outL[o + 8] = l8[1];
}

// ---------------------------------------------------------------------------
// xp = X @ W_ih + b  (split-3 bf16 GEMM). 128x128 tile, 4 waves (2x2).
// Unchanged from round 3/4. rt==0 blocks fuse tanh + h0-plane emit.
// ---------------------------------------------------------------------------
__global__ __launch_bounds__(256) void xp_gemm(const float* __restrict__ X,
                                               const short* __restrict__ WTh,
                                               const short* __restrict__ WTl,
                                               const float* __restrict__ bias,
                                               float* __restrict__ C,
                                               short* __restrict__ h0H,
                                               short* __restrict__ h0L) {
    __shared__ short Ah_s[128 * 40];
    __shared__ short Al_s[128 * 40];

    const int tid = threadIdx.x, lane = tid & 63, wave = tid >> 6;
    const int l15 = lane & 15, lg = lane >> 4;

    const int gid = blockIdx.x;
    const int rt = ((gid >> 8) << 4) | (gid & 15);
    const int ct = (gid >> 4) & 15;
    const int row0 = rt * 128, col0 = ct * 128;
    const int wm = (wave >> 1) * 64, wn = (wave & 1) * 64;

    const int sr = tid >> 3, sc = (tid & 7) * 4;
    const float* gA = X + (size_t)(row0 + sr) * DD + sc;

    size_t brow[4];
#pragma unroll
    for (int n = 0; n < 4; ++n)
        brow[n] = (size_t)(col0 + wn + n * 16 + l15) * DD + lg * 8;

    f32x4 acc[4][4] = {};

    for (int k0 = 0; k0 < DD; k0 += 32) {
        f32x4 av[4];
        short4v h4[4], l4[4];
#pragma unroll
        for (int i = 0; i < 4; ++i)
            av[i] = *(const f32x4*)(gA + (size_t)(32 * i) * DD + k0);
#pragma unroll
        for (int i = 0; i < 4; ++i)
#pragma unroll
            for (int q = 0; q < 4; ++q) {
                short h, l; split2(av[i][q], h, l);
                h4[i][q] = h; l4[i][q] = l;
            }
        short8 bh[4], bl[4];
#pragma unroll
        for (int n = 0; n < 4; ++n) {
            bh[n] = *(const short8*)&WTh[brow[n] + k0];
            bl[n] = *(const short8*)&WTl[brow[n] + k0];
        }
        __syncthreads();
#pragma unroll
        for (int i = 0; i < 4; ++i) {
            *(short4v*)&Ah_s[(sr + 32 * i) * 40 + sc] = h4[i];
            *(short4v*)&Al_s[(sr + 32 * i) * 40 + sc] = l4[i];
        }
        __syncthreads();
        short8 ah[4], al[4];
#pragma unroll
        for (int m = 0; m < 4; ++m) {
            const int ro = (wm + m * 16 + l15) * 40 + lg * 8;
            ah[m] = *(const short8*)&Ah_s[ro];
            al[m] = *(const short8*)&Al_s[ro];
        }
#pragma unroll
        for (int m = 0; m < 4; ++m)
#pragma unroll
            for (int n = 0; n < 4; ++n) {
                acc[m][n] = MFMA(ah[m], bh[n], acc[m][n]);
                acc[m][n] = MFMA(ah[m], bl[n], acc[m][n]);
                acc[m][n] = MFMA(al[m], bh[n], acc[m][n]);
            }
    }

    float bv[4];
#pragma unroll
    for (int n = 0; n < 4; ++n) bv[n] = bias[col0 + wn + n * 16 + l15];

    if (rt == 0) {
#pragma unroll
        for (int m = 0; m < 4; ++m)
#pragma unroll
            for (int n = 0; n < 4; ++n)
#pragma unroll
                for (int i = 0; i < 4; ++i) {
                    const int row = wm + m * 16 + lg * 4 + i;
                    const int col = col0 + wn + n * 16 + l15;
                    const float t = tanhf(acc[m][n][i] + bv[n]);
                    const size_t o = (size_t)row * HH + col;
                    C[o] = t;
                    short h, l; split2(t, h, l);
                    h0H[o] = h; h0L[o] = l;
                }
    } else {
#pragma unroll
        for (int m = 0; m < 4; ++m)
#pragma unroll
            for (int n = 0; n < 4; ++n)
#pragma unroll
                for (int i = 0; i < 4; ++i) {
                    const int row = row0 + wm + m * 16 + lg * 4 + i;
                    const int col = col0 + wn + n * 16 + l15;
                    C[(size_t)row * HH + col] = acc[m][n][i] + bv[n];
                }
    }
}

// ---------------------------------------------------------------------------
// Persistent scan: all 255 steps in one dispatch. 256 blocks x 512 threads.
// Block (mr,nc): rows mr*32.., cols nc*32..; bid = mr*64+nc -> XCD = nc%8, so
// each W 32-col strip is read by 4 blocks on ONE XCD (W-lo L2-resident, 2MB/XCD)
// and W-hi lives in LDS (128KB, swizzled) for the whole scan.
// h exchange: sc1 (AGENT-scope relaxed atomic) stores/loads through L3 — NO
// threadfence, NO buffer_wbl2/inv, L2 contents never invalidated.
// Sync: per-mr-group (64 blocks) monotonic counter barrier; block (mr,nc) only
// depends on blocks with the same mr (it reads h rows mr*32..+31 only).
// Residency: LDS 147456B -> 1 block/CU; 256 blocks <= 256 CUs -> no deadlock.
// ---------------------------------------------------------------------------
__global__ __launch_bounds__(512) void rnn_scan(const short* __restrict__ WTh,
                                                const short* __restrict__ WTl,
                                                short* __restrict__ hA_hi, short* __restrict__ hA_lo,
                                                short* __restrict__ hB_hi, short* __restrict__ hB_lo,
                                                float* __restrict__ out,
                                                float* __restrict__ final_state,
                                                unsigned* __restrict__ bar) {
    __shared__ short Whi[32 * 2048];    // 128 KB: W-hi strip, swizzled
    __shared__ float red[4][1024];      // 16 KB: cross-wave reduce

    const int tid = threadIdx.x, lane = tid & 63, wave = tid >> 6;
    const int l15 = lane & 15, lg = lane >> 4;
    const int mr = blockIdx.x >> 6, nc = blockIdx.x & 63;
    const int m0 = mr * 32, n0 = nc * 32;
    unsigned* grp_cnt = bar + mr * 64;  // 256B apart per mr group

    // one-time LDS fill of W-hi strip (swizzle: byte ^= (col&7)<<4)
    for (int it = 0; it < 16; ++it) {
        const int ci  = it * 512 + tid;   // 8192 16B-chunks
        const int col = ci >> 8;          // 0..31
        const int kc  = ci & 255;
        const short8 v = *(const short8*)&WTh[(size_t)(n0 + col) * HH + kc * 8];
        const int byte = ((col << 12) + (kc << 4)) ^ ((col & 7) << 4);
        *(short8*)((char*)Whi + byte) = v;
    }
    __syncthreads();

    const size_t a0 = (size_t)(m0 + l15) * HH;
    const size_t a1 = a0 + (size_t)16 * HH;
    const size_t b0 = (size_t)(n0 + l15) * HH;
    const size_t b1 = b0 + (size_t)16 * HH;
    const int kbase = wave * 256 + lg * 8;
    const int colbase0 = l15 << 12,        swz0 = (l15 & 7) << 4;
    const int colbase1 = (16 + l15) << 12, swz1 = (l15 & 7) << 4;

    const int e = tid * 2, er = e >> 5, ec = e & 31;       // epilogue coords
    const size_t po = (size_t)(m0 + er) * HH + n0 + ec;

    for (int t = 1; t < LSEQ; ++t) {
        const short* hHp = (t & 1) ? hA_hi : hB_hi;   // parity of t-1
        const short* hLp = (t & 1) ? hA_lo : hB_lo;
        short* oH = (t & 1) ? hB_hi : hA_hi;
        short* oL = (t & 1) ? hB_lo : hA_lo;
        float* io = out + (size_t)t * BH;

        f32x4 acc00 = {}, acc01 = {}, acc10 = {}, acc11 = {};
#pragma unroll
        for (int kt = 0; kt < 8; ++kt) {
            const int k = kbase + kt * 32;
            const short8 ah0 = load_h16(&hHp[a0 + k]);
            const short8 ah1 = load_h16(&hHp[a1 + k]);
            const short8 al0 = load_h16(&hLp[a0 + k]);
            const short8 al1 = load_h16(&hLp[a1 + k]);
            const short8 bl0 = *(const short8*)&WTl[b0 + k];
            const short8 bl1 = *(const short8*)&WTl[b1 + k];
            const short8 bh0 = *(const short8*)((const char*)Whi + (colbase0 | ((2 * k) ^ swz0)));
            const short8 bh1 = *(const short8*)((const char*)Whi + (colbase1 | ((2 * k) ^ swz1)));

            acc00 = MFMA(ah0, bh0, acc00); acc00 = MFMA(ah0, bl0, acc00); acc00 = MFMA(al0, bh0, acc00);
            acc01 = MFMA(ah0, bh1, acc01); acc01 = MFMA(ah0, bl1, acc01); acc01 = MFMA(al0, bh1, acc01);
            acc10 = MFMA(ah1, bh0, acc10); acc10 = MFMA(ah1, bl0, acc10); acc10 = MFMA(al1, bh0, acc10);
            acc11 = MFMA(ah1, bh1, acc11); acc11 = MFMA(ah1, bl1, acc11); acc11 = MFMA(al1, bh1, acc11);
        }

        // two-phase cross-wave reduce (8 partials -> red[0..3])
        f32x4 am[2][2] = {{acc00, acc01}, {acc10, acc11}};
        if (wave < 4) {
#pragma unroll
            for (int m = 0; m < 2; ++m)
#pragma unroll
                for (int n = 0; n < 2; ++n)
#pragma unroll
                    for (int i = 0; i < 4; ++i)
                        red[wave][(m * 16 + lg * 4 + i) * 32 + n * 16 + l15] = am[m][n][i];
        }
        __syncthreads();
        if (wave >= 4) {
#pragma unroll
            for (int m = 0; m < 2; ++m)
#pragma unroll
                for (int n = 0; n < 2; ++n)
#pragma unroll
                    for (int i = 0; i < 4; ++i)
                        red[wave - 4][(m * 16 + lg * 4 + i) * 32 + n * 16 + l15] += am[m][n][i];
        }
        __syncthreads();

        // epilogue: 2 elems/thread — 4 partials + xp + tanh; h planes via sc1
        {
            float* iop = io + po;
            const float2 xv = *(const float2*)iop;
            const int base = er * 32 + ec;
            const float2 r0 = *(const float2*)&red[0][base];
            const float2 r1 = *(const float2*)&red[1][base];
            const float2 r2 = *(const float2*)&red[2][base];
            const float2 r3 = *(const float2*)&red[3][base];
            const float t0 = tanhf(xv.x + r0.x + r1.x + r2.x + r3.x);
            const float t1 = tanhf(xv.y + r0.y + r1.y + r2.y + r3.y);
            *(float2*)iop = make_float2(t0, t1);
            short h0s, l0s, h1s, l1s;
            split2(t0, h0s, l0s); split2(t1, h1s, l1s);
            const unsigned ph = (unsigned)(unsigned short)h0s | ((unsigned)(unsigned short)h1s << 16);
            const unsigned pl = (unsigned)(unsigned short)l0s | ((unsigned)(unsigned short)l1s << 16);
            __hip_atomic_store((unsigned*)&oH[po], ph, __ATOMIC_RELAXED, __HIP_MEMORY_SCOPE_AGENT);
            __hip_atomic_store((unsigned*)&oL[po], pl, __ATOMIC_RELAXED, __HIP_MEMORY_SCOPE_AGENT);
            if (t == LSEQ - 1)
                *(float2*)(final_state + po) = make_float2(t0, t1);
        }

        // per-mr-group barrier: monotonic counter, no reset, no fences.
        // __syncthreads drains each wave's vmcnt (sc1 stores at L3) first.
        if (t != LSEQ - 1) {
            __syncthreads();
            if (tid == 0) {
                __hip_atomic_fetch_add(grp_cnt, 1u, __ATOMIC_RELAXED, __HIP_MEMORY_SCOPE_AGENT);
                const unsigned target = (unsigned)t * 64u;
                while (__hip_atomic_load(grp_cnt, __ATOMIC_RELAXED, __HIP_MEMORY_SCOPE_AGENT) < target)
                    __builtin_amdgcn_s_sleep(2);
            }
            __syncthreads();
        }
    }
}

// ---------------------------------------------------------------------------
extern "C" void kernel_launch(void* const* d_in, const int* in_sizes, int n_in,
                              void* d_out, int out_size, void* d_ws, size_t ws_size,
                              hipStream_t stream) {
    (void)in_sizes; (void)n_in; (void)out_size; (void)ws_size;

    const float* X   = (const float*)d_in[0];
    const float* Wih = (const float*)d_in[1];
    const float* Whh = (const float*)d_in[2];
    const float* b   = (const float*)d_in[3];
    float* out = (float*)d_out;

    char* ws = (char*)d_ws;
    short* WihTh = (short*)(ws);
    short* WihTl = (short*)(ws + (size_t) 8*1024*1024);
    short* WhhTh = (short*)(ws + (size_t)16*1024*1024);
    short* WhhTl = (short*)(ws + (size_t)24*1024*1024);
    short* hA_hi = (short*)(ws + (size_t)32*1024*1024);
    short* hA_lo = (short*)(ws + (size_t)32*1024*1024 + 512*1024);
    short* hB_hi = (short*)(ws + (size_t)33*1024*1024);
    short* hB_lo = (short*)(ws + (size_t)33*1024*1024 + 512*1024);
    unsigned* bar = (unsigned*)(ws + (size_t)34*1024*1024);   // 4 x 64 uints

    // zero barrier counters each call (ws poisoned once, never restored)
    hipMemsetAsync(bar, 0, 1024, stream);

    dim3 tg(32, 32);
    transpose_split<<<tg, 256, 0, stream>>>(Wih, WihTh, WihTl);
    transpose_split<<<tg, 256, 0, stream>>>(Whh, WhhTh, WhhTl);

    // xp GEMM (t=0 blocks also produce h0 = tanh(xp[0]) + planes into hA)
    xp_gemm<<<4096, 256, 0, stream>>>(X, WihTh, WihTl, b, out, hA_hi, hA_lo);

    // persistent scan: t = 1..255 in one dispatch, writes final state too
    rnn_scan<<<NBLK, 512, 0, stream>>>(WhhTh, WhhTl, hA_hi, hA_lo, hB_hi, hB_lo,
                                       out, out + (size_t)LSEQ * BH, bar);
}